// Round 3
// baseline (138.531 us; speedup 1.0000x reference)
//
#include <hip/hip_runtime.h>
#include <cfloat>
#include <cstdint>

#define NV 50257
#define NB 2048
#define NK 5
#define TOPK 10
#define NT 256
#define CAP 1024
#define THR 0.99f

__device__ __forceinline__ void insert_top(float (&top)[TOPK], float v) {
    // precondition: v > top[TOPK-1]
    top[TOPK-1] = v;
#pragma unroll
    for (int i = TOPK - 1; i > 0; --i) {
        float a = top[i-1], b = top[i];
        top[i-1] = fmaxf(a, b);
        top[i]   = fminf(a, b);
    }
}

__global__ __launch_bounds__(NT, 8) void embert_row_kernel(
        const float* __restrict__ probas,
        const int*   __restrict__ labels,
        float*       __restrict__ row_out,
        int*         __restrict__ counter,
        float*       __restrict__ out) {
    const int row = blockIdx.x;
    const int tid = threadIdx.x;
    const float* __restrict__ p = probas + (size_t)row * NV;

    __shared__ float cvals[CAP];
    __shared__ int   cidx[CAP];
    __shared__ int   cnt;
    __shared__ float labval[NK];
    __shared__ float sm[NT][TOPK];
    __shared__ int   is_last;

    const int l0 = labels[row*NK + 0];
    const int l1 = labels[row*NK + 1];
    const int l2 = labels[row*NK + 2];
    const int l3 = labels[row*NK + 3];
    const int l4 = labels[row*NK + 4];

    // Early gather of labeled probas (latency hides under the stream).
    if (tid < NK) labval[tid] = p[labels[row*NK + tid]];
    if (tid == 0) cnt = 0;
    __syncthreads();

    auto emit = [&](float v, int j) {
        int slot = atomicAdd(&cnt, 1);
        if (slot < CAP) { cvals[slot] = v; cidx[slot] = j; }
    };
    auto proc = [&](const float4& v, int j) {
        float m = fmaxf(fmaxf(v.x, v.y), fmaxf(v.z, v.w));
        if (m > THR) {
            if (v.x > THR) emit(v.x, j);
            if (v.y > THR) emit(v.y, j + 1);
            if (v.z > THR) emit(v.z, j + 2);
            if (v.w > THR) emit(v.w, j + 3);
        }
    };

    // Row base is only 4B-aligned: scalar prologue to 16B, float4 body, tail.
    const int mis = (int)(((uintptr_t)p >> 2) & 3);
    const int pre = (4 - mis) & 3;
    const int nvec = (NV - pre) >> 2;
    const int tail_start = pre + nvec * 4;

    if (tid < pre && p[tid] > THR) emit(p[tid], tid);

    const float4* __restrict__ p4 = (const float4*)(p + pre);
    int vi = tid;
    for (; vi + NT < nvec; vi += 2 * NT) {
        float4 a = p4[vi];
        float4 b = p4[vi + NT];
        proc(a, pre + vi * 4);
        proc(b, pre + (vi + NT) * 4);
    }
    if (vi < nvec) { float4 a = p4[vi]; proc(a, pre + vi * 4); }

    if (tid < NV - tail_start && p[tail_start + tid] > THR)
        emit(p[tail_start + tid], tail_start + tid);

    __syncthreads();
    const int n = cnt;
    const bool fast = (n >= TOPK + NK) && (n <= CAP);

    float top[TOPK];
#pragma unroll
    for (int i = 0; i < TOPK; ++i) top[i] = -FLT_MAX;

    if (fast) {
        for (int c = tid; c < n; c += NT) {
            float v = cvals[c];
            int   j = cidx[c];
            if (v > top[TOPK-1]) {
                if (j != l0 && j != l1 && j != l2 && j != l3 && j != l4) {
                    insert_top(top, v);
                }
            }
        }
    } else {
        // Fallback: full scan (correct for any input; never taken for uniform).
        auto consider = [&](float v, int j) {
            if (v > top[TOPK-1]) {
                if (j != l0 && j != l1 && j != l2 && j != l3 && j != l4) {
                    insert_top(top, v);
                }
            }
        };
        if (tid < pre) consider(p[tid], tid);
        for (int wi = tid; wi < nvec; wi += NT) {
            float4 v = p4[wi];
            const int j = pre + wi * 4;
            consider(v.x, j);
            consider(v.y, j + 1);
            consider(v.z, j + 2);
            consider(v.w, j + 3);
        }
        if (tid < NV - tail_start) consider(p[tail_start + tid], tail_start + tid);
    }

    // Block tree-merge of per-thread sorted top-10 lists.
#pragma unroll
    for (int i = 0; i < TOPK; ++i) sm[tid][i] = top[i];
    __syncthreads();

    for (int off = NT / 2; off >= 1; off >>= 1) {
        if (tid < off) {
#pragma unroll
            for (int m = 0; m < TOPK; ++m) {
                float v = sm[tid + off][m];
                if (v > top[TOPK-1]) {
                    insert_top(top, v);
                } else {
                    break;  // partner list sorted desc
                }
            }
#pragma unroll
            for (int i = 0; i < TOPK; ++i) sm[tid][i] = top[i];
        }
        __syncthreads();
    }

    if (tid == 0) {
        float wrong_sum = 0.f;
#pragma unroll
        for (int i = 0; i < TOPK; ++i) wrong_sum += top[i];
        const float wrong_avg = wrong_sum * (1.0f / TOPK);

        int ls[NK] = {l0, l1, l2, l3, l4};
        float csum = 0.f;
        int   nn   = 0;
#pragma unroll
        for (int a = 0; a < NK; ++a) {
            bool dup = false;
#pragma unroll
            for (int b = 0; b < NK; ++b) {
                if (b < a) dup |= (ls[a] == ls[b]);
            }
            if (!dup) { csum += labval[a]; ++nn; }
        }
        row_out[row] = wrong_avg - csum / (float)nn;

        __threadfence();                    // publish row_out[row]
        int prev = atomicAdd(counter, 1);   // device-scope
        is_last = (prev == NB - 1);
    }
    __syncthreads();

    if (is_last) {
        __threadfence();                    // acquire: see all row_out writes
        float s = 0.f;
        for (int i = tid; i < NB; i += NT) s += row_out[i];
#pragma unroll
        for (int off = 32; off >= 1; off >>= 1) s += __shfl_down(s, off, 64);
        if ((tid & 63) == 0) sm[0][tid >> 6] = s;
        __syncthreads();
        if (tid == 0) {
            float t = sm[0][0] + sm[0][1] + sm[0][2] + sm[0][3];
            out[0] = t * (1.0f / NB);
        }
    }
}

extern "C" void kernel_launch(void* const* d_in, const int* in_sizes, int n_in,
                              void* d_out, int out_size, void* d_ws, size_t ws_size,
                              hipStream_t stream) {
    const float* probas = (const float*)d_in[0];
    const int*   labels = (const int*)d_in[1];
    float* out  = (float*)d_out;
    float* rows = (float*)d_ws;                               // NB floats
    int*   counter = (int*)((char*)d_ws + NB * sizeof(float)); // 1 int

    hipMemsetAsync(counter, 0, sizeof(int), stream);
    embert_row_kernel<<<NB, NT, 0, stream>>>(probas, labels, rows, counter, out);
}

// Round 4
// 87.523 us; speedup vs baseline: 1.5828x; 1.5828x over previous
//
#include <hip/hip_runtime.h>
#include <cfloat>
#include <cstdint>

#define NV 50257
#define NB 2048
#define NK 5
#define TOPK 10
#define NT 256
#define CAP 1024
#define THR 0.99f

__device__ __forceinline__ void insert_top(float (&top)[TOPK], float v) {
    // precondition: v > top[TOPK-1]
    top[TOPK-1] = v;
#pragma unroll
    for (int i = TOPK - 1; i > 0; --i) {
        float a = top[i-1], b = top[i];
        top[i-1] = fmaxf(a, b);
        top[i]   = fminf(a, b);
    }
}

__global__ __launch_bounds__(NT, 8) void embert_row_kernel(
        const float* __restrict__ probas,
        const int*   __restrict__ labels,
        float*       __restrict__ row_out) {
    const int row = blockIdx.x;
    const int tid = threadIdx.x;
    const float* __restrict__ p = probas + (size_t)row * NV;

    __shared__ float cvals[CAP];
    __shared__ int   cidx[CAP];
    __shared__ int   cnt;
    __shared__ float labval[NK];
    __shared__ float sm[NT][TOPK];   // fallback path only

    const int l0 = labels[row*NK + 0];
    const int l1 = labels[row*NK + 1];
    const int l2 = labels[row*NK + 2];
    const int l3 = labels[row*NK + 3];
    const int l4 = labels[row*NK + 4];

    // Parallel early gather of labeled probas (latency hides under the stream).
    if (tid < NK) labval[tid] = p[labels[row*NK + tid]];
    if (tid == 0) cnt = 0;
    __syncthreads();

    // ---- Pass 1: collect candidates > THR into LDS (value + index) ----
    auto emit = [&](float v, int j) {
        if (v > THR) {
            int slot = atomicAdd(&cnt, 1);
            if (slot < CAP) { cvals[slot] = v; cidx[slot] = j; }
        }
    };
    auto emit4 = [&](const float4& v, int j) {
        emit(v.x, j);
        emit(v.y, j + 1);
        emit(v.z, j + 2);
        emit(v.w, j + 3);
    };

    // Row base is only 4B-aligned: scalar prologue to 16B, float4 body, tail.
    const int mis = (int)(((uintptr_t)p >> 2) & 3);
    const int pre = (4 - mis) & 3;
    const int nvec = (NV - pre) >> 2;
    const int tail_start = pre + nvec * 4;

    if (tid < pre) emit(p[tid], tid);

    const float4* __restrict__ p4 = (const float4*)(p + pre);
    int vi = tid;
    // 4 independent loads in flight before any consumption.
    for (; vi + 3 * NT < nvec; vi += 4 * NT) {
        float4 a = p4[vi];
        float4 b = p4[vi + NT];
        float4 c = p4[vi + 2 * NT];
        float4 d = p4[vi + 3 * NT];
        emit4(a, pre + vi * 4);
        emit4(b, pre + (vi + NT) * 4);
        emit4(c, pre + (vi + 2 * NT) * 4);
        emit4(d, pre + (vi + 3 * NT) * 4);
    }
    for (; vi < nvec; vi += NT) {
        float4 a = p4[vi];
        emit4(a, pre + vi * 4);
    }

    if (tid < NV - tail_start) emit(p[tail_start + tid], tail_start + tid);

    __syncthreads();
    const int n = cnt;
    const bool fast = (n >= TOPK + NK) && (n <= CAP);

    float top[TOPK];
#pragma unroll
    for (int i = 0; i < TOPK; ++i) top[i] = -FLT_MAX;

    if (fast) {
        // ---- Single-wave selection: wave 0 scans LDS candidates, shfl merge ----
        if (tid < 64) {
            for (int c = tid; c < n; c += 64) {
                float v = cvals[c];
                int   j = cidx[c];
                if (v > top[TOPK-1]) {
                    if (j != l0 && j != l1 && j != l2 && j != l3 && j != l4) {
                        insert_top(top, v);
                    }
                }
            }
#pragma unroll
            for (int off = 32; off >= 1; off >>= 1) {
                float other[TOPK];
#pragma unroll
                for (int i = 0; i < TOPK; ++i) other[i] = __shfl_xor(top[i], off, 64);
#pragma unroll
                for (int i = 0; i < TOPK; ++i) {
                    if (other[i] > top[TOPK-1]) insert_top(top, other[i]);
                }
            }
        }
        // thread 0 (lane 0 of wave 0) now holds the block's top-10.
    } else {
        // ---- Fallback: full scan + 256-thread LDS tree merge (any input) ----
        auto consider = [&](float v, int j) {
            if (v > top[TOPK-1]) {
                if (j != l0 && j != l1 && j != l2 && j != l3 && j != l4) {
                    insert_top(top, v);
                }
            }
        };
        if (tid < pre) consider(p[tid], tid);
        for (int wi = tid; wi < nvec; wi += NT) {
            float4 v = p4[wi];
            const int j = pre + wi * 4;
            consider(v.x, j);
            consider(v.y, j + 1);
            consider(v.z, j + 2);
            consider(v.w, j + 3);
        }
        if (tid < NV - tail_start) consider(p[tail_start + tid], tail_start + tid);

#pragma unroll
        for (int i = 0; i < TOPK; ++i) sm[tid][i] = top[i];
        __syncthreads();
        for (int off = NT / 2; off >= 1; off >>= 1) {
            if (tid < off) {
#pragma unroll
                for (int m = 0; m < TOPK; ++m) {
                    float v = sm[tid + off][m];
                    if (v > top[TOPK-1]) {
                        insert_top(top, v);
                    } else {
                        break;
                    }
                }
#pragma unroll
                for (int i = 0; i < TOPK; ++i) sm[tid][i] = top[i];
            }
            __syncthreads();
        }
    }

    if (tid == 0) {
        float wrong_sum = 0.f;
#pragma unroll
        for (int i = 0; i < TOPK; ++i) wrong_sum += top[i];
        const float wrong_avg = wrong_sum * (1.0f / TOPK);

        int ls[NK] = {l0, l1, l2, l3, l4};
        float csum = 0.f;
        int   nn   = 0;
#pragma unroll
        for (int a = 0; a < NK; ++a) {
            bool dup = false;
#pragma unroll
            for (int b = 0; b < NK; ++b) {
                if (b < a) dup |= (ls[a] == ls[b]);
            }
            if (!dup) { csum += labval[a]; ++nn; }
        }
        row_out[row] = wrong_avg - csum / (float)nn;
    }
}

__global__ __launch_bounds__(NT) void embert_reduce_kernel(
        const float* __restrict__ row_out,
        float*       __restrict__ out) {
    const int tid = threadIdx.x;
    float s = 0.f;
    for (int i = tid; i < NB; i += NT) s += row_out[i];
#pragma unroll
    for (int off = 32; off >= 1; off >>= 1) s += __shfl_down(s, off, 64);
    __shared__ float ws[NT / 64];
    if ((tid & 63) == 0) ws[tid >> 6] = s;
    __syncthreads();
    if (tid == 0) {
        float t = 0.f;
#pragma unroll
        for (int w = 0; w < NT / 64; ++w) t += ws[w];
        out[0] = t * (1.0f / NB);
    }
}

extern "C" void kernel_launch(void* const* d_in, const int* in_sizes, int n_in,
                              void* d_out, int out_size, void* d_ws, size_t ws_size,
                              hipStream_t stream) {
    const float* probas = (const float*)d_in[0];
    const int*   labels = (const int*)d_in[1];
    float* out  = (float*)d_out;
    float* rows = (float*)d_ws;   // NB floats of scratch

    embert_row_kernel<<<NB, NT, 0, stream>>>(probas, labels, rows);
    embert_reduce_kernel<<<1, NT, 0, stream>>>(rows, out);
}

// Round 5
// 83.960 us; speedup vs baseline: 1.6500x; 1.0424x over previous
//
#include <hip/hip_runtime.h>
#include <cfloat>
#include <cstdint>

#define NV 50257
#define NB 2048
#define NK 5
#define TOPK 10
#define NT 256
#define CAP 256
#define THR 0.9985f

__device__ __forceinline__ void insert_top(float (&top)[TOPK], float v) {
    // precondition: v > top[TOPK-1]
    top[TOPK-1] = v;
#pragma unroll
    for (int i = TOPK - 1; i > 0; --i) {
        float a = top[i-1], b = top[i];
        top[i-1] = fmaxf(a, b);
        top[i]   = fminf(a, b);
    }
}

__global__ __launch_bounds__(NT, 8) void embert_row_kernel(
        const float* __restrict__ probas,
        const int*   __restrict__ labels,
        float*       __restrict__ row_out) {
    const int row = blockIdx.x;
    const int tid = threadIdx.x;
    const float* __restrict__ p = probas + (size_t)row * NV;

    __shared__ float cvals[CAP];
    __shared__ int   cidx[CAP];
    __shared__ int   cnt;
    __shared__ float labval[NK];
    __shared__ float sm[NT][TOPK];   // fallback path only

    const int l0 = labels[row*NK + 0];
    const int l1 = labels[row*NK + 1];
    const int l2 = labels[row*NK + 2];
    const int l3 = labels[row*NK + 3];
    const int l4 = labels[row*NK + 4];

    // Parallel early gather of labeled probas (latency hides under the stream).
    if (tid < NK) labval[tid] = p[labels[row*NK + tid]];
    if (tid == 0) cnt = 0;
    __syncthreads();

    // ---- Pass 1: collect candidates > THR into LDS (value + index) ----
    auto emit = [&](float v, int j) {
        if (v > THR) {
            int slot = atomicAdd(&cnt, 1);
            if (slot < CAP) { cvals[slot] = v; cidx[slot] = j; }
        }
    };
    auto emit4 = [&](const float4& v, int j) {
        emit(v.x, j);
        emit(v.y, j + 1);
        emit(v.z, j + 2);
        emit(v.w, j + 3);
    };

    // Row base is only 4B-aligned: scalar prologue to 16B, float4 body, tail.
    const int mis = (int)(((uintptr_t)p >> 2) & 3);
    const int pre = (4 - mis) & 3;
    const int nvec = (NV - pre) >> 2;
    const int tail_start = pre + nvec * 4;

    if (tid < pre) emit(p[tid], tid);

    const float4* __restrict__ p4 = (const float4*)(p + pre);
    int vi = tid;
    // 4 independent loads in flight before any consumption.
    for (; vi + 3 * NT < nvec; vi += 4 * NT) {
        float4 a = p4[vi];
        float4 b = p4[vi + NT];
        float4 c = p4[vi + 2 * NT];
        float4 d = p4[vi + 3 * NT];
        emit4(a, pre + vi * 4);
        emit4(b, pre + (vi + NT) * 4);
        emit4(c, pre + (vi + 2 * NT) * 4);
        emit4(d, pre + (vi + 3 * NT) * 4);
    }
    for (; vi < nvec; vi += NT) {
        float4 a = p4[vi];
        emit4(a, pre + vi * 4);
    }

    if (tid < NV - tail_start) emit(p[tail_start + tid], tail_start + tid);

    __syncthreads();
    const int n = cnt;
    const bool fast = (n >= TOPK + NK) && (n <= CAP);

    float top[TOPK];
#pragma unroll
    for (int i = 0; i < TOPK; ++i) top[i] = -FLT_MAX;

    if (fast) {
        // ---- Single-wave selection: wave 0 scans LDS candidates, shfl merge ----
        if (tid < 64) {
            for (int c = tid; c < n; c += 64) {
                float v = cvals[c];
                int   j = cidx[c];
                if (v > top[TOPK-1]) {
                    if (j != l0 && j != l1 && j != l2 && j != l3 && j != l4) {
                        insert_top(top, v);
                    }
                }
            }
#pragma unroll
            for (int off = 32; off >= 1; off >>= 1) {
                float other[TOPK];
#pragma unroll
                for (int i = 0; i < TOPK; ++i) other[i] = __shfl_xor(top[i], off, 64);
#pragma unroll
                for (int i = 0; i < TOPK; ++i) {
                    if (other[i] > top[TOPK-1]) insert_top(top, other[i]);
                }
            }
        }
        // thread 0 (lane 0 of wave 0) now holds the block's top-10.
    } else {
        // ---- Fallback: full scan + 256-thread LDS tree merge (any input) ----
        auto consider = [&](float v, int j) {
            if (v > top[TOPK-1]) {
                if (j != l0 && j != l1 && j != l2 && j != l3 && j != l4) {
                    insert_top(top, v);
                }
            }
        };
        if (tid < pre) consider(p[tid], tid);
        for (int wi = tid; wi < nvec; wi += NT) {
            float4 v = p4[wi];
            const int j = pre + wi * 4;
            consider(v.x, j);
            consider(v.y, j + 1);
            consider(v.z, j + 2);
            consider(v.w, j + 3);
        }
        if (tid < NV - tail_start) consider(p[tail_start + tid], tail_start + tid);

#pragma unroll
        for (int i = 0; i < TOPK; ++i) sm[tid][i] = top[i];
        __syncthreads();
        for (int off = NT / 2; off >= 1; off >>= 1) {
            if (tid < off) {
#pragma unroll
                for (int m = 0; m < TOPK; ++m) {
                    float v = sm[tid + off][m];
                    if (v > top[TOPK-1]) {
                        insert_top(top, v);
                    } else {
                        break;
                    }
                }
#pragma unroll
                for (int i = 0; i < TOPK; ++i) sm[tid][i] = top[i];
            }
            __syncthreads();
        }
    }

    if (tid == 0) {
        float wrong_sum = 0.f;
#pragma unroll
        for (int i = 0; i < TOPK; ++i) wrong_sum += top[i];
        const float wrong_avg = wrong_sum * (1.0f / TOPK);

        int ls[NK] = {l0, l1, l2, l3, l4};
        float csum = 0.f;
        int   nn   = 0;
#pragma unroll
        for (int a = 0; a < NK; ++a) {
            bool dup = false;
#pragma unroll
            for (int b = 0; b < NK; ++b) {
                if (b < a) dup |= (ls[a] == ls[b]);
            }
            if (!dup) { csum += labval[a]; ++nn; }
        }
        row_out[row] = wrong_avg - csum / (float)nn;
    }
}

__global__ __launch_bounds__(NT) void embert_reduce_kernel(
        const float* __restrict__ row_out,
        float*       __restrict__ out) {
    const int tid = threadIdx.x;
    float s = 0.f;
    for (int i = tid; i < NB; i += NT) s += row_out[i];
#pragma unroll
    for (int off = 32; off >= 1; off >>= 1) s += __shfl_down(s, off, 64);
    __shared__ float ws[NT / 64];
    if ((tid & 63) == 0) ws[tid >> 6] = s;
    __syncthreads();
    if (tid == 0) {
        float t = 0.f;
#pragma unroll
        for (int w = 0; w < NT / 64; ++w) t += ws[w];
        out[0] = t * (1.0f / NB);
    }
}

extern "C" void kernel_launch(void* const* d_in, const int* in_sizes, int n_in,
                              void* d_out, int out_size, void* d_ws, size_t ws_size,
                              hipStream_t stream) {
    const float* probas = (const float*)d_in[0];
    const int*   labels = (const int*)d_in[1];
    float* out  = (float*)d_out;
    float* rows = (float*)d_ws;   // NB floats of scratch

    embert_row_kernel<<<NB, NT, 0, stream>>>(probas, labels, rows);
    embert_reduce_kernel<<<1, NT, 0, stream>>>(rows, out);
}

// Round 6
// 76.439 us; speedup vs baseline: 1.8123x; 1.0984x over previous
//
#include <hip/hip_runtime.h>
#include <cfloat>
#include <cstdint>

#define NV 50257
#define NB 2048
#define NK 5
#define TOPK 10
#define NT 256
#define CAP 256
#define THR 0.9985f

typedef float f32x4 __attribute__((ext_vector_type(4)));

__device__ __forceinline__ void insert_top(float (&top)[TOPK], float v) {
    // precondition: v > top[TOPK-1]
    top[TOPK-1] = v;
#pragma unroll
    for (int i = TOPK - 1; i > 0; --i) {
        float a = top[i-1], b = top[i];
        top[i-1] = fmaxf(a, b);
        top[i]   = fminf(a, b);
    }
}

__global__ __launch_bounds__(NT, 8) void embert_row_kernel(
        const float* __restrict__ probas,
        const int*   __restrict__ labels,
        float*       __restrict__ row_out) {
    const int row = blockIdx.x;
    const int tid = threadIdx.x;
    const float* __restrict__ p = probas + (size_t)row * NV;

    __shared__ float cvals[CAP];
    __shared__ int   cidx[CAP];
    __shared__ int   cnt;
    __shared__ float labval[NK];
    __shared__ float sm[NT][TOPK];   // fallback path only

    const int l0 = labels[row*NK + 0];
    const int l1 = labels[row*NK + 1];
    const int l2 = labels[row*NK + 2];
    const int l3 = labels[row*NK + 3];
    const int l4 = labels[row*NK + 4];

    // Parallel early gather of labeled probas (latency hides under the stream).
    if (tid < NK) labval[tid] = p[labels[row*NK + tid]];
    if (tid == 0) cnt = 0;
    __syncthreads();

    // ---- Pass 1: collect candidates > THR into LDS (value + index) ----
    auto emit = [&](float v, int j) {
        if (v > THR) {
            int slot = atomicAdd(&cnt, 1);
            if (slot < CAP) { cvals[slot] = v; cidx[slot] = j; }
        }
    };
    auto emit4 = [&](const f32x4& v, int j) {
        emit(v[0], j);
        emit(v[1], j + 1);
        emit(v[2], j + 2);
        emit(v[3], j + 3);
    };

    // Row base is only 4B-aligned: scalar prologue to 16B, float4 body, tail.
    const int mis = (int)(((uintptr_t)p >> 2) & 3);
    const int pre = (4 - mis) & 3;
    const int nvec = (NV - pre) >> 2;
    const int tail_start = pre + nvec * 4;

    if (tid < pre) emit(p[tid], tid);

    const f32x4* __restrict__ p4 = (const f32x4*)(p + pre);
    int vi = tid;
    // 4 independent non-temporal loads in flight before any consumption.
    for (; vi + 3 * NT < nvec; vi += 4 * NT) {
        f32x4 a = __builtin_nontemporal_load(p4 + vi);
        f32x4 b = __builtin_nontemporal_load(p4 + vi + NT);
        f32x4 c = __builtin_nontemporal_load(p4 + vi + 2 * NT);
        f32x4 d = __builtin_nontemporal_load(p4 + vi + 3 * NT);
        emit4(a, pre + vi * 4);
        emit4(b, pre + (vi + NT) * 4);
        emit4(c, pre + (vi + 2 * NT) * 4);
        emit4(d, pre + (vi + 3 * NT) * 4);
    }
    for (; vi < nvec; vi += NT) {
        f32x4 a = __builtin_nontemporal_load(p4 + vi);
        emit4(a, pre + vi * 4);
    }

    if (tid < NV - tail_start) emit(p[tail_start + tid], tail_start + tid);

    __syncthreads();
    const int n = cnt;
    const bool fast = (n >= TOPK + NK) && (n <= CAP);

    float top[TOPK];
#pragma unroll
    for (int i = 0; i < TOPK; ++i) top[i] = -FLT_MAX;

    if (fast) {
        // ---- Single-wave selection: wave 0 scans LDS candidates, shfl merge ----
        if (tid < 64) {
            for (int c = tid; c < n; c += 64) {
                float v = cvals[c];
                int   j = cidx[c];
                if (v > top[TOPK-1]) {
                    if (j != l0 && j != l1 && j != l2 && j != l3 && j != l4) {
                        insert_top(top, v);
                    }
                }
            }
#pragma unroll
            for (int off = 32; off >= 1; off >>= 1) {
                float other[TOPK];
#pragma unroll
                for (int i = 0; i < TOPK; ++i) other[i] = __shfl_xor(top[i], off, 64);
#pragma unroll
                for (int i = 0; i < TOPK; ++i) {
                    if (other[i] > top[TOPK-1]) insert_top(top, other[i]);
                }
            }
        }
        // thread 0 (lane 0 of wave 0) now holds the block's top-10.
    } else {
        // ---- Fallback: full scan + 256-thread LDS tree merge (any input) ----
        auto consider = [&](float v, int j) {
            if (v > top[TOPK-1]) {
                if (j != l0 && j != l1 && j != l2 && j != l3 && j != l4) {
                    insert_top(top, v);
                }
            }
        };
        if (tid < pre) consider(p[tid], tid);
        for (int wi = tid; wi < nvec; wi += NT) {
            f32x4 v = p4[wi];
            const int j = pre + wi * 4;
            consider(v[0], j);
            consider(v[1], j + 1);
            consider(v[2], j + 2);
            consider(v[3], j + 3);
        }
        if (tid < NV - tail_start) consider(p[tail_start + tid], tail_start + tid);

#pragma unroll
        for (int i = 0; i < TOPK; ++i) sm[tid][i] = top[i];
        __syncthreads();
        for (int off = NT / 2; off >= 1; off >>= 1) {
            if (tid < off) {
#pragma unroll
                for (int m = 0; m < TOPK; ++m) {
                    float v = sm[tid + off][m];
                    if (v > top[TOPK-1]) {
                        insert_top(top, v);
                    } else {
                        break;
                    }
                }
#pragma unroll
                for (int i = 0; i < TOPK; ++i) sm[tid][i] = top[i];
            }
            __syncthreads();
        }
    }

    if (tid == 0) {
        float wrong_sum = 0.f;
#pragma unroll
        for (int i = 0; i < TOPK; ++i) wrong_sum += top[i];
        const float wrong_avg = wrong_sum * (1.0f / TOPK);

        int ls[NK] = {l0, l1, l2, l3, l4};
        float csum = 0.f;
        int   nn   = 0;
#pragma unroll
        for (int a = 0; a < NK; ++a) {
            bool dup = false;
#pragma unroll
            for (int b = 0; b < NK; ++b) {
                if (b < a) dup |= (ls[a] == ls[b]);
            }
            if (!dup) { csum += labval[a]; ++nn; }
        }
        row_out[row] = wrong_avg - csum / (float)nn;
    }
}

__global__ __launch_bounds__(NT) void embert_reduce_kernel(
        const float* __restrict__ row_out,
        float*       __restrict__ out) {
    const int tid = threadIdx.x;
    float s = 0.f;
    for (int i = tid; i < NB; i += NT) s += row_out[i];
#pragma unroll
    for (int off = 32; off >= 1; off >>= 1) s += __shfl_down(s, off, 64);
    __shared__ float ws[NT / 64];
    if ((tid & 63) == 0) ws[tid >> 6] = s;
    __syncthreads();
    if (tid == 0) {
        float t = 0.f;
#pragma unroll
        for (int w = 0; w < NT / 64; ++w) t += ws[w];
        out[0] = t * (1.0f / NB);
    }
}

extern "C" void kernel_launch(void* const* d_in, const int* in_sizes, int n_in,
                              void* d_out, int out_size, void* d_ws, size_t ws_size,
                              hipStream_t stream) {
    const float* probas = (const float*)d_in[0];
    const int*   labels = (const int*)d_in[1];
    float* out  = (float*)d_out;
    float* rows = (float*)d_ws;   // NB floats of scratch

    embert_row_kernel<<<NB, NT, 0, stream>>>(probas, labels, rows);
    embert_reduce_kernel<<<1, NT, 0, stream>>>(rows, out);
}

// Round 7
// 74.984 us; speedup vs baseline: 1.8475x; 1.0194x over previous
//
#include <hip/hip_runtime.h>
#include <cfloat>
#include <cstdint>

#define NV 50257
#define NB 2048
#define NK 5
#define TOPK 10
#define NT 256
#define CAP 256
#define THR 0.9985f

typedef float f32x4 __attribute__((ext_vector_type(4)));

__device__ __forceinline__ void insert_top(float (&top)[TOPK], float v) {
    // precondition: v > top[TOPK-1]
    top[TOPK-1] = v;
#pragma unroll
    for (int i = TOPK - 1; i > 0; --i) {
        float a = top[i-1], b = top[i];
        top[i-1] = fmaxf(a, b);
        top[i]   = fminf(a, b);
    }
}

__global__ __launch_bounds__(NT, 8) void embert_row_kernel(
        const float* __restrict__ probas,
        const int*   __restrict__ labels,
        float*       __restrict__ row_out) {
    const int row = blockIdx.x;
    const int tid = threadIdx.x;
    const float* __restrict__ p = probas + (size_t)row * NV;

    __shared__ float cvals[CAP];
    __shared__ int   cidx[CAP];
    __shared__ int   cnt;
    __shared__ float labval[NK];
    __shared__ float sm[NT][TOPK];   // fallback path only

    const int l0 = labels[row*NK + 0];
    const int l1 = labels[row*NK + 1];
    const int l2 = labels[row*NK + 2];
    const int l3 = labels[row*NK + 3];
    const int l4 = labels[row*NK + 4];

    // Issue the label gather into registers NOW (no barrier in between) —
    // the s_waitcnt lands at the LDS write after pass 1, so the ~900-cycle
    // scatter latency hides under the 200 KB stream.
    float my_labval = 0.f;
    if (tid < NK) my_labval = p[labels[row*NK + tid]];

    if (tid == 0) cnt = 0;
    __syncthreads();   // cnt=0 visible before emits

    // ---- Pass 1: collect candidates > THR into LDS (value + index) ----
    auto emit = [&](float v, int j) {
        if (v > THR) {
            int slot = atomicAdd(&cnt, 1);
            if (slot < CAP) { cvals[slot] = v; cidx[slot] = j; }
        }
    };
    auto emit4 = [&](const f32x4& v, int j) {
        emit(v[0], j);
        emit(v[1], j + 1);
        emit(v[2], j + 2);
        emit(v[3], j + 3);
    };

    // Row base is only 4B-aligned: scalar prologue to 16B, float4 body, tail.
    const int mis = (int)(((uintptr_t)p >> 2) & 3);
    const int pre = (4 - mis) & 3;
    const int nvec = (NV - pre) >> 2;
    const int tail_start = pre + nvec * 4;

    if (tid < pre) emit(p[tid], tid);

    const f32x4* __restrict__ p4 = (const f32x4*)(p + pre);
    int vi = tid;
    // 4 independent non-temporal loads in flight before any consumption.
    for (; vi + 3 * NT < nvec; vi += 4 * NT) {
        f32x4 a = __builtin_nontemporal_load(p4 + vi);
        f32x4 b = __builtin_nontemporal_load(p4 + vi + NT);
        f32x4 c = __builtin_nontemporal_load(p4 + vi + 2 * NT);
        f32x4 d = __builtin_nontemporal_load(p4 + vi + 3 * NT);
        emit4(a, pre + vi * 4);
        emit4(b, pre + (vi + NT) * 4);
        emit4(c, pre + (vi + 2 * NT) * 4);
        emit4(d, pre + (vi + 3 * NT) * 4);
    }
    for (; vi < nvec; vi += NT) {
        f32x4 a = __builtin_nontemporal_load(p4 + vi);
        emit4(a, pre + vi * 4);
    }

    if (tid < NV - tail_start) emit(p[tail_start + tid], tail_start + tid);

    // Deferred labval publish (gather latency long since covered).
    if (tid < NK) labval[tid] = my_labval;

    __syncthreads();
    const int n = cnt;
    const bool fast = (n >= TOPK + NK) && (n <= CAP);

    float top[TOPK];
#pragma unroll
    for (int i = 0; i < TOPK; ++i) top[i] = -FLT_MAX;

    if (fast) {
        // ---- Single-wave selection: wave 0 scans LDS candidates, shfl merge ----
        if (tid < 64) {
            for (int c = tid; c < n; c += 64) {
                float v = cvals[c];
                int   j = cidx[c];
                if (v > top[TOPK-1]) {
                    if (j != l0 && j != l1 && j != l2 && j != l3 && j != l4) {
                        insert_top(top, v);
                    }
                }
            }
#pragma unroll
            for (int off = 32; off >= 1; off >>= 1) {
                float other[TOPK];
#pragma unroll
                for (int i = 0; i < TOPK; ++i) other[i] = __shfl_xor(top[i], off, 64);
#pragma unroll
                for (int i = 0; i < TOPK; ++i) {
                    if (other[i] > top[TOPK-1]) insert_top(top, other[i]);
                }
            }
        }
        // thread 0 (lane 0 of wave 0) now holds the block's top-10.
    } else {
        // ---- Fallback: full scan + 256-thread LDS tree merge (any input) ----
        auto consider = [&](float v, int j) {
            if (v > top[TOPK-1]) {
                if (j != l0 && j != l1 && j != l2 && j != l3 && j != l4) {
                    insert_top(top, v);
                }
            }
        };
        if (tid < pre) consider(p[tid], tid);
        for (int wi = tid; wi < nvec; wi += NT) {
            f32x4 v = p4[wi];
            const int j = pre + wi * 4;
            consider(v[0], j);
            consider(v[1], j + 1);
            consider(v[2], j + 2);
            consider(v[3], j + 3);
        }
        if (tid < NV - tail_start) consider(p[tail_start + tid], tail_start + tid);

#pragma unroll
        for (int i = 0; i < TOPK; ++i) sm[tid][i] = top[i];
        __syncthreads();
        for (int off = NT / 2; off >= 1; off >>= 1) {
            if (tid < off) {
#pragma unroll
                for (int m = 0; m < TOPK; ++m) {
                    float v = sm[tid + off][m];
                    if (v > top[TOPK-1]) {
                        insert_top(top, v);
                    } else {
                        break;
                    }
                }
#pragma unroll
                for (int i = 0; i < TOPK; ++i) sm[tid][i] = top[i];
            }
            __syncthreads();
        }
    }

    if (tid == 0) {
        float wrong_sum = 0.f;
#pragma unroll
        for (int i = 0; i < TOPK; ++i) wrong_sum += top[i];
        const float wrong_avg = wrong_sum * (1.0f / TOPK);

        int ls[NK] = {l0, l1, l2, l3, l4};
        float csum = 0.f;
        int   nn   = 0;
#pragma unroll
        for (int a = 0; a < NK; ++a) {
            bool dup = false;
#pragma unroll
            for (int b = 0; b < NK; ++b) {
                if (b < a) dup |= (ls[a] == ls[b]);
            }
            if (!dup) { csum += labval[a]; ++nn; }
        }
        row_out[row] = wrong_avg - csum / (float)nn;
    }
}

__global__ __launch_bounds__(NT) void embert_reduce_kernel(
        const float* __restrict__ row_out,
        float*       __restrict__ out) {
    const int tid = threadIdx.x;
    const f32x4* __restrict__ r4 = (const f32x4*)row_out;
    float s = 0.f;
#pragma unroll
    for (int k = 0; k < NB / (4 * NT); ++k) {
        f32x4 v = r4[tid + k * NT];
        s += v[0] + v[1] + v[2] + v[3];
    }
#pragma unroll
    for (int off = 32; off >= 1; off >>= 1) s += __shfl_down(s, off, 64);
    __shared__ float ws[NT / 64];
    if ((tid & 63) == 0) ws[tid >> 6] = s;
    __syncthreads();
    if (tid == 0) {
        float t = 0.f;
#pragma unroll
        for (int w = 0; w < NT / 64; ++w) t += ws[w];
        out[0] = t * (1.0f / NB);
    }
}

extern "C" void kernel_launch(void* const* d_in, const int* in_sizes, int n_in,
                              void* d_out, int out_size, void* d_ws, size_t ws_size,
                              hipStream_t stream) {
    const float* probas = (const float*)d_in[0];
    const int*   labels = (const int*)d_in[1];
    float* out  = (float*)d_out;
    float* rows = (float*)d_ws;   // NB floats of scratch

    embert_row_kernel<<<NB, NT, 0, stream>>>(probas, labels, rows);
    embert_reduce_kernel<<<1, NT, 0, stream>>>(rows, out);
}